// Round 1
// baseline (1198.006 us; speedup 1.0000x reference)
//
#include <hip/hip_runtime.h>
#include <math.h>

#define BATCH 16
#define TWIN 8
#define SEQIN 129
#define DMODEL 192
#define GLEN 2048           // TWIN*256
#define NH 24
#define HD 32
#define DS 128
#define NCH 920             // stored proj channels: 0..895 = x|B (conv), 896..919 = dt
#define MTOT (BATCH*GLEN)   // 32768

__device__ __forceinline__ float softplus_f(float x){
  return x > 20.f ? x : log1pf(expf(x));
}
__device__ __forceinline__ float silu_f(float x){
  return x / (1.f + expf(-x));
}

// Build PE-added, sliced, padded input: xg[b][g][d], g = t*256 + s
__global__ __launch_bounds__(256) void k_build_xg(const float* __restrict__ in,
                                                  float* __restrict__ xg){
  int idx = blockIdx.x*256 + threadIdx.x;
  if (idx >= MTOT*DMODEL) return;
  int d = idx % DMODEL;
  int rest = idx / DMODEL;
  int g = rest % GLEN;
  int b = rest / GLEN;
  int t = g >> 8, s = g & 255;
  float v = 0.f;
  if (s < 128) v = in[((size_t)(b*TWIN + t)*SEQIN + (s+1))*DMODEL + d];
  float div = expf(-(float)(d & ~1) * (logf(10000.f)/(float)DMODEL));
  float ang = (float)t * div;
  v += (d & 1) ? cosf(ang) : sinf(ang);
  xg[idx] = v;
}

// proj[m][c] = sum_d xg[m][d] * W[srcrow(c)][d]; W row r = in_proj_w row 768+r
// stored c<896 -> W row c; c in [896,920) -> W row 1024+(c-896)
__global__ __launch_bounds__(256) void k_gemm_proj(const float* __restrict__ xg,
    const float* __restrict__ inw, float* __restrict__ proj){
  __shared__ float As[16][64];
  __shared__ float Bs[16][64];
  int tid = threadIdx.x;
  int m0 = blockIdx.x*64, n0 = blockIdx.y*64;
  int ty = tid >> 4, tx = tid & 15;
  int lr = tid >> 2, lq = tid & 3;
  float acc[4][4] = {};
  for (int k0 = 0; k0 < DMODEL; k0 += 16){
    float4 av = *(const float4*)(xg + (size_t)(m0+lr)*DMODEL + k0 + lq*4);
    As[lq*4+0][lr] = av.x; As[lq*4+1][lr] = av.y;
    As[lq*4+2][lr] = av.z; As[lq*4+3][lr] = av.w;
    int cg = n0 + lr;
    float4 bv = make_float4(0.f,0.f,0.f,0.f);
    if (cg < NCH){
      int row = (cg < 896) ? (768 + cg) : (1792 + (cg - 896));
      bv = *(const float4*)(inw + (size_t)row*DMODEL + k0 + lq*4);
    }
    Bs[lq*4+0][lr] = bv.x; Bs[lq*4+1][lr] = bv.y;
    Bs[lq*4+2][lr] = bv.z; Bs[lq*4+3][lr] = bv.w;
    __syncthreads();
    #pragma unroll
    for (int kk = 0; kk < 16; kk++){
      float4 a = *(const float4*)&As[kk][ty*4];
      float4 bq = *(const float4*)&Bs[kk][tx*4];
      float avr[4] = {a.x, a.y, a.z, a.w};
      float bvr[4] = {bq.x, bq.y, bq.z, bq.w};
      #pragma unroll
      for (int i=0;i<4;i++)
        #pragma unroll
        for (int j=0;j<4;j++)
          acc[i][j] += avr[i]*bvr[j];
    }
    __syncthreads();
  }
  #pragma unroll
  for (int i=0;i<4;i++){
    int m = m0 + ty*4 + i;
    #pragma unroll
    for (int j=0;j<4;j++){
      int n = n0 + tx*4 + j;
      if (n < NCH) proj[(size_t)m*NCH + n] = acc[i][j];
    }
  }
}

// Per (b,h): dt = softplus(dt_raw + dt_bias); logdA = dt*(-exp(A_log));
// w[g] = exp(csum_total - csum[g]) * dt[g]   (window-independent!)
__global__ __launch_bounds__(256) void k_scan_w(const float* __restrict__ proj,
    const float* __restrict__ dt_bias, const float* __restrict__ A_log,
    float* __restrict__ wbuf){
  int h = blockIdx.x, b = blockIdx.y;
  int tid = threadIdx.x;
  float dtb = dt_bias[h];
  float negA = -expf(A_log[h]);
  float dtv[8], pre[8];
  float run = 0.f;
  size_t base = (size_t)b*GLEN;
  #pragma unroll
  for (int i=0;i<8;i++){
    int g = tid*8 + i;
    float v = proj[(base + g)*NCH + 896 + h];
    float dt = softplus_f(v + dtb);
    run += dt * negA;
    dtv[i] = dt; pre[i] = run;
  }
  __shared__ float s[256];
  float tot_thread = run;
  s[tid] = run;
  __syncthreads();
  for (int off=1; off<256; off<<=1){
    float v = (tid>=off) ? s[tid-off] : 0.f;
    __syncthreads();
    s[tid] += v;
    __syncthreads();
  }
  float total = s[255];
  float excl = s[tid] - tot_thread;
  #pragma unroll
  for (int i=0;i<8;i++){
    int g = tid*8+i;
    float w = expf(total - (excl + pre[i])) * dtv[i];
    wbuf[(base + g)*NH + h] = w;
  }
}

// Global (window-0 semantics) conv+silu, then fold heads:
// y[g,p] = sum_h w[g,h]*xs[h*32+p]; Bm[g,n] = xs[768+n]. yB row = [y(32)|Bm(128)]
__global__ __launch_bounds__(256) void k_conv_fold(const float* __restrict__ proj,
    const float* __restrict__ conv_w, const float* __restrict__ conv_b,
    const float* __restrict__ wbuf, float* __restrict__ yB){
  int g = blockIdx.x, b = blockIdx.y;
  int tid = threadIdx.x;
  __shared__ float xs[896];
  __shared__ float wv[NH];
  size_t rbase = (size_t)b*GLEN;
  if (tid < NH) wv[tid] = wbuf[(rbase + g)*NH + tid];
  for (int c = tid; c < 896; c += 256){
    float a = conv_b[c];
    #pragma unroll
    for (int k=0;k<4;k++){
      int gp = g - 3 + k;
      if (gp >= 0) a += proj[(rbase+gp)*NCH + c] * conv_w[c*4+k];
    }
    xs[c] = silu_f(a);
  }
  __syncthreads();
  if (tid < 32){
    float y = 0.f;
    #pragma unroll
    for (int h=0;h<NH;h++) y += wv[h]*xs[h*32+tid];
    yB[(rbase+g)*160 + tid] = y;
  } else if (tid < 160){
    yB[(rbase+g)*160 + tid] = xs[768 + tid - 32];
  }
}

// Per (b,t): feat[p,n] = sum_{g>=t*256} y[g,p]*Bm[g,n].
// For t>0 the first 3 positions are recomputed with the window's zero-padded conv.
__global__ __launch_bounds__(256) void k_accum(const float* __restrict__ proj,
    const float* __restrict__ conv_w, const float* __restrict__ conv_b,
    const float* __restrict__ wbuf, const float* __restrict__ yB,
    float* __restrict__ feat){
  int t = blockIdx.x, b = blockIdx.y;
  int tid = threadIdx.x;
  __shared__ float xs[896];
  __shared__ float wv[NH];
  __shared__ float buf[8*160];
  int p0 = (tid >> 5) * 4;
  int n0 = (tid & 31) * 4;
  float acc[4][4] = {};
  size_t rbase = (size_t)b*GLEN;
  int g0 = t*256;
  int gstart = g0;
  if (t > 0){
    gstart = g0 + 3;
    for (int gi=0; gi<3; gi++){
      int g = g0 + gi;
      if (tid < NH) wv[tid] = wbuf[(rbase+g)*NH + tid];
      for (int c = tid; c < 896; c += 256){
        float a = conv_b[c];
        #pragma unroll
        for (int k=0;k<4;k++){
          int gp = g - 3 + k;
          if (gp >= g0) a += proj[(rbase+gp)*NCH + c]*conv_w[c*4+k];
        }
        xs[c] = silu_f(a);
      }
      __syncthreads();
      if (tid < 32){
        float y = 0.f;
        #pragma unroll
        for (int h=0;h<NH;h++) y += wv[h]*xs[h*32+tid];
        buf[gi*160 + tid] = y;
      } else if (tid < 160){
        buf[gi*160 + tid] = xs[768 + tid - 32];
      }
      __syncthreads();
    }
    #pragma unroll
    for (int gi=0; gi<3; gi++){
      float4 yv = *(const float4*)&buf[gi*160 + p0];
      float4 bv = *(const float4*)&buf[gi*160 + 32 + n0];
      float ya[4] = {yv.x,yv.y,yv.z,yv.w};
      float ba[4] = {bv.x,bv.y,bv.z,bv.w};
      #pragma unroll
      for (int i=0;i<4;i++)
        #pragma unroll
        for (int j=0;j<4;j++)
          acc[i][j] += ya[i]*ba[j];
    }
    __syncthreads();
  }
  for (int gb = gstart; gb < GLEN; gb += 8){
    int cnt = min(8, GLEN - gb);
    int nelem = cnt*160;
    for (int idx = tid; idx < nelem; idx += 256)
      buf[idx] = yB[(rbase+gb)*160 + idx];
    __syncthreads();
    for (int gi=0; gi<cnt; gi++){
      float4 yv = *(const float4*)&buf[gi*160 + p0];
      float4 bv = *(const float4*)&buf[gi*160 + 32 + n0];
      float ya[4] = {yv.x,yv.y,yv.z,yv.w};
      float ba[4] = {bv.x,bv.y,bv.z,bv.w};
      #pragma unroll
      for (int i=0;i<4;i++)
        #pragma unroll
        for (int j=0;j<4;j++)
          acc[i][j] += ya[i]*ba[j];
    }
    __syncthreads();
  }
  size_t fb = (size_t)(b*TWIN + t)*32;
  #pragma unroll
  for (int i=0;i<4;i++)
    #pragma unroll
    for (int j=0;j<4;j++)
      feat[(fb + p0+i)*128 + n0+j] = acc[i][j];
}

// out[bt][k] = feat[bt] . cls_w[k] + cls_b[k]
__global__ __launch_bounds__(256) void k_classifier(const float* __restrict__ feat,
    const float* __restrict__ cls_w, const float* __restrict__ cls_b,
    float* __restrict__ out){
  int bt = blockIdx.x;
  int tid = threadIdx.x;
  __shared__ float fl[4096];
  for (int idx=tid; idx<4096; idx+=256) fl[idx] = feat[(size_t)bt*4096 + idx];
  __syncthreads();
  int wave = tid >> 6, lane = tid & 63;
  for (int k = wave; k < 100; k += 4){
    float s = 0.f;
    const float* wr = cls_w + (size_t)k*4096;
    for (int j=0;j<64;j++){
      int f = j*64 + lane;
      s += fl[f]*wr[f];
    }
    #pragma unroll
    for (int off=32; off>0; off>>=1) s += __shfl_down(s, off, 64);
    if (lane==0) out[bt*100 + k] = s + cls_b[k];
  }
}

extern "C" void kernel_launch(void* const* d_in, const int* in_sizes, int n_in,
                              void* d_out, int out_size, void* d_ws, size_t ws_size,
                              hipStream_t stream){
  const float* inputs    = (const float*)d_in[0];
  const float* in_proj_w = (const float*)d_in[1];
  const float* conv_w    = (const float*)d_in[2];
  const float* conv_b    = (const float*)d_in[3];
  const float* dt_bias   = (const float*)d_in[4];
  const float* A_log     = (const float*)d_in[5];
  const float* cls_w     = (const float*)d_in[6];
  const float* cls_b     = (const float*)d_in[7];
  float* out = (float*)d_out;

  float* xg   = (float*)d_ws;                       // MTOT*192
  float* proj = xg   + (size_t)MTOT*DMODEL;         // MTOT*920
  float* wbuf = proj + (size_t)MTOT*NCH;            // MTOT*24
  float* yB   = wbuf + (size_t)MTOT*NH;             // MTOT*160
  float* feat = yB   + (size_t)MTOT*160;            // 128*4096
  size_t need = ((size_t)MTOT*DMODEL + (size_t)MTOT*NCH + (size_t)MTOT*NH
               + (size_t)MTOT*160 + (size_t)128*4096) * sizeof(float);
  if (ws_size < need) return;  // loud failure rather than OOB scribble

  k_build_xg  <<<(MTOT*DMODEL + 255)/256, 256, 0, stream>>>(inputs, xg);
  k_gemm_proj <<<dim3(MTOT/64, (NCH+63)/64), 256, 0, stream>>>(xg, in_proj_w, proj);
  k_scan_w    <<<dim3(NH, BATCH), 256, 0, stream>>>(proj, dt_bias, A_log, wbuf);
  k_conv_fold <<<dim3(GLEN, BATCH), 256, 0, stream>>>(proj, conv_w, conv_b, wbuf, yB);
  k_accum     <<<dim3(TWIN, BATCH), 256, 0, stream>>>(proj, conv_w, conv_b, wbuf, yB, feat);
  k_classifier<<<128, 256, 0, stream>>>(feat, cls_w, cls_b, out);
}

// Round 2
// 460.551 us; speedup vs baseline: 2.6012x; 2.6012x over previous
//
#include <hip/hip_runtime.h>
#include <math.h>

#define BATCH 16
#define TWIN 8
#define SEQIN 129
#define DMODEL 192
#define GLEN 2048           // TWIN*256
#define NH 24
#define HD 32
#define DS 128
#define NCH 920             // stored proj channels: 0..895 = x|B (conv), 896..919 = dt
#define MTOT (BATCH*GLEN)   // 32768

__device__ __forceinline__ float softplus_f(float x){
  return x > 20.f ? x : log1pf(expf(x));
}
__device__ __forceinline__ float silu_f(float x){
  return x / (1.f + expf(-x));
}

// Build PE-added, sliced, padded input: xg[b][g][d], g = t*256 + s
__global__ __launch_bounds__(256) void k_build_xg(const float* __restrict__ in,
                                                  float* __restrict__ xg){
  int idx = blockIdx.x*256 + threadIdx.x;
  if (idx >= MTOT*DMODEL) return;
  int d = idx % DMODEL;
  int rest = idx / DMODEL;
  int g = rest % GLEN;
  int b = rest / GLEN;
  int t = g >> 8, s = g & 255;
  float v = 0.f;
  if (s < 128) v = in[((size_t)(b*TWIN + t)*SEQIN + (s+1))*DMODEL + d];
  float div = expf(-(float)(d & ~1) * (logf(10000.f)/(float)DMODEL));
  float ang = (float)t * div;
  v += (d & 1) ? cosf(ang) : sinf(ang);
  xg[idx] = v;
}

// proj[m][c] = sum_d xg[m][d] * W[srcrow(c)][d]
__global__ __launch_bounds__(256) void k_gemm_proj(const float* __restrict__ xg,
    const float* __restrict__ inw, float* __restrict__ proj){
  __shared__ float As[16][64];
  __shared__ float Bs[16][64];
  int tid = threadIdx.x;
  int m0 = blockIdx.x*64, n0 = blockIdx.y*64;
  int ty = tid >> 4, tx = tid & 15;
  int lr = tid >> 2, lq = tid & 3;
  float acc[4][4] = {};
  for (int k0 = 0; k0 < DMODEL; k0 += 16){
    float4 av = *(const float4*)(xg + (size_t)(m0+lr)*DMODEL + k0 + lq*4);
    As[lq*4+0][lr] = av.x; As[lq*4+1][lr] = av.y;
    As[lq*4+2][lr] = av.z; As[lq*4+3][lr] = av.w;
    int cg = n0 + lr;
    float4 bv = make_float4(0.f,0.f,0.f,0.f);
    if (cg < NCH){
      int row = (cg < 896) ? (768 + cg) : (1792 + (cg - 896));
      bv = *(const float4*)(inw + (size_t)row*DMODEL + k0 + lq*4);
    }
    Bs[lq*4+0][lr] = bv.x; Bs[lq*4+1][lr] = bv.y;
    Bs[lq*4+2][lr] = bv.z; Bs[lq*4+3][lr] = bv.w;
    __syncthreads();
    #pragma unroll
    for (int kk = 0; kk < 16; kk++){
      float4 a = *(const float4*)&As[kk][ty*4];
      float4 bq = *(const float4*)&Bs[kk][tx*4];
      float avr[4] = {a.x, a.y, a.z, a.w};
      float bvr[4] = {bq.x, bq.y, bq.z, bq.w};
      #pragma unroll
      for (int i=0;i<4;i++)
        #pragma unroll
        for (int j=0;j<4;j++)
          acc[i][j] += avr[i]*bvr[j];
    }
    __syncthreads();
  }
  #pragma unroll
  for (int i=0;i<4;i++){
    int m = m0 + ty*4 + i;
    #pragma unroll
    for (int j=0;j<4;j++){
      int n = n0 + tx*4 + j;
      if (n < NCH) proj[(size_t)m*NCH + n] = acc[i][j];
    }
  }
}

// Per (b,h): w[g] = exp(csum_total - csum[g]) * dt[g]   (window-independent)
__global__ __launch_bounds__(256) void k_scan_w(const float* __restrict__ proj,
    const float* __restrict__ dt_bias, const float* __restrict__ A_log,
    float* __restrict__ wbuf){
  int h = blockIdx.x, b = blockIdx.y;
  int tid = threadIdx.x;
  float dtb = dt_bias[h];
  float negA = -expf(A_log[h]);
  float dtv[8], pre[8];
  float run = 0.f;
  size_t base = (size_t)b*GLEN;
  #pragma unroll
  for (int i=0;i<8;i++){
    int g = tid*8 + i;
    float v = proj[(base + g)*NCH + 896 + h];
    float dt = softplus_f(v + dtb);
    run += dt * negA;
    dtv[i] = dt; pre[i] = run;
  }
  __shared__ float s[256];
  float tot_thread = run;
  s[tid] = run;
  __syncthreads();
  for (int off=1; off<256; off<<=1){
    float v = (tid>=off) ? s[tid-off] : 0.f;
    __syncthreads();
    s[tid] += v;
    __syncthreads();
  }
  float total = s[255];
  float excl = s[tid] - tot_thread;
  #pragma unroll
  for (int i=0;i<8;i++){
    int g = tid*8+i;
    float w = expf(total - (excl + pre[i])) * dtv[i];
    wbuf[(base + g)*NH + h] = w;
  }
}

// Global conv+silu, fold heads: yB row = [y(32)|Bm(128)]
__global__ __launch_bounds__(256) void k_conv_fold(const float* __restrict__ proj,
    const float* __restrict__ conv_w, const float* __restrict__ conv_b,
    const float* __restrict__ wbuf, float* __restrict__ yB){
  int g = blockIdx.x, b = blockIdx.y;
  int tid = threadIdx.x;
  __shared__ float xs[896];
  __shared__ float wv[NH];
  size_t rbase = (size_t)b*GLEN;
  if (tid < NH) wv[tid] = wbuf[(rbase + g)*NH + tid];
  for (int c = tid; c < 896; c += 256){
    float a = conv_b[c];
    #pragma unroll
    for (int k=0;k<4;k++){
      int gp = g - 3 + k;
      if (gp >= 0) a += proj[(rbase+gp)*NCH + c] * conv_w[c*4+k];
    }
    xs[c] = silu_f(a);
  }
  __syncthreads();
  if (tid < 32){
    float y = 0.f;
    #pragma unroll
    for (int h=0;h<NH;h++) y += wv[h]*xs[h*32+tid];
    yB[(rbase+g)*160 + tid] = y;
  } else if (tid < 160){
    yB[(rbase+g)*160 + tid] = xs[768 + tid - 32];
  }
}

// Chunk partials: partial[b][t][sub][32][128] over 64 positions each
__global__ __launch_bounds__(256) void k_partial(const float* __restrict__ yB,
    float* __restrict__ partial){
  int t = blockIdx.x & 7, b = blockIdx.x >> 3, sub = blockIdx.y;
  int tid = threadIdx.x;
  __shared__ float buf[8*160];
  int p0 = (tid >> 5) * 4;
  int n0 = (tid & 31) * 4;
  float acc[4][4] = {};
  size_t rbase = (size_t)b*GLEN;
  int gstart = t*256 + sub*64;
  for (int gb = gstart; gb < gstart+64; gb += 8){
    for (int idx = tid; idx < 8*160; idx += 256)
      buf[idx] = yB[(rbase+gb)*160 + idx];
    __syncthreads();
    #pragma unroll
    for (int gi=0; gi<8; gi++){
      float4 yv = *(const float4*)&buf[gi*160 + p0];
      float4 bv = *(const float4*)&buf[gi*160 + 32 + n0];
      float ya[4] = {yv.x,yv.y,yv.z,yv.w};
      float ba[4] = {bv.x,bv.y,bv.z,bv.w};
      #pragma unroll
      for (int i=0;i<4;i++)
        #pragma unroll
        for (int j=0;j<4;j++)
          acc[i][j] += ya[i]*ba[j];
    }
    __syncthreads();
  }
  size_t pb = (((size_t)(b*TWIN + t))*4 + sub)*4096;
  #pragma unroll
  for (int i=0;i<4;i++)
    #pragma unroll
    for (int j=0;j<4;j++)
      partial[pb + (p0+i)*128 + n0+j] = acc[i][j];
}

// Suffix-sum partials over t: feat[b][t] = sum_{t'>=t} sum_sub partial[b][t'][sub]
__global__ __launch_bounds__(256) void k_suffix(const float* __restrict__ partial,
    float* __restrict__ feat){
  int b = blockIdx.y;
  int e = blockIdx.x*256 + threadIdx.x;   // 0..4095
  float s = 0.f;
  for (int t = TWIN-1; t >= 0; t--){
    size_t pb = ((size_t)(b*TWIN + t))*4*4096;
    #pragma unroll
    for (int sub=0; sub<4; sub++) s += partial[pb + sub*4096 + e];
    feat[((size_t)(b*TWIN + t))*4096 + e] = s;
  }
}

// Boundary corrections for t>0: first 3 positions of each window use a
// zero-history conv; replace global contribution with window contribution.
__global__ __launch_bounds__(256) void k_correct(const float* __restrict__ proj,
    const float* __restrict__ conv_w, const float* __restrict__ conv_b,
    const float* __restrict__ wbuf, float* __restrict__ feat){
  int t = blockIdx.x + 1, b = blockIdx.y;
  int tid = threadIdx.x;
  __shared__ float xsw[896], xsg[896];
  __shared__ float wv[NH];
  __shared__ float bufw[3*160], bufg[3*160];
  size_t rbase = (size_t)b*GLEN;
  int g0 = t*256;
  for (int gi=0; gi<3; gi++){
    int g = g0 + gi;
    if (tid < NH) wv[tid] = wbuf[(rbase+g)*NH + tid];
    for (int c = tid; c < 896; c += 256){
      float aw = conv_b[c], ag = conv_b[c];
      #pragma unroll
      for (int k=0;k<4;k++){
        int gp = g - 3 + k;
        float term = proj[(rbase+gp)*NCH + c] * conv_w[c*4+k];
        ag += term;
        if (gp >= g0) aw += term;
      }
      xsw[c] = silu_f(aw);
      xsg[c] = silu_f(ag);
    }
    __syncthreads();
    if (tid < 32){
      float yw = 0.f, yg = 0.f;
      #pragma unroll
      for (int h=0;h<NH;h++){ yw += wv[h]*xsw[h*32+tid]; yg += wv[h]*xsg[h*32+tid]; }
      bufw[gi*160 + tid] = yw;
      bufg[gi*160 + tid] = yg;
    } else if (tid < 160){
      bufw[gi*160 + tid] = xsw[768 + tid - 32];
      bufg[gi*160 + tid] = xsg[768 + tid - 32];
    }
    __syncthreads();
  }
  int p0 = (tid >> 5) * 4;
  int n0 = (tid & 31) * 4;
  float acc[4][4] = {};
  #pragma unroll
  for (int gi=0; gi<3; gi++){
    float4 ywv = *(const float4*)&bufw[gi*160 + p0];
    float4 bwv = *(const float4*)&bufw[gi*160 + 32 + n0];
    float4 ygv = *(const float4*)&bufg[gi*160 + p0];
    float4 bgv = *(const float4*)&bufg[gi*160 + 32 + n0];
    float yw[4]={ywv.x,ywv.y,ywv.z,ywv.w}, bw[4]={bwv.x,bwv.y,bwv.z,bwv.w};
    float yg[4]={ygv.x,ygv.y,ygv.z,ygv.w}, bg[4]={bgv.x,bgv.y,bgv.z,bgv.w};
    #pragma unroll
    for (int i=0;i<4;i++)
      #pragma unroll
      for (int j=0;j<4;j++)
        acc[i][j] += yw[i]*bw[j] - yg[i]*bg[j];
  }
  size_t fb = (size_t)(b*TWIN + t)*4096;
  #pragma unroll
  for (int i=0;i<4;i++)
    #pragma unroll
    for (int j=0;j<4;j++)
      feat[fb + (p0+i)*128 + n0+j] += acc[i][j];
}

// out[bt][k] = feat[bt] . cls_w[k] + cls_b[k]; one wave per (bt,k)
__global__ __launch_bounds__(256) void k_classifier(const float* __restrict__ feat,
    const float* __restrict__ cls_w, const float* __restrict__ cls_b,
    float* __restrict__ out){
  int bt = blockIdx.x;
  int wave = threadIdx.x >> 6, lane = threadIdx.x & 63;
  int k = blockIdx.y*4 + wave;
  if (k >= 100) return;
  const float* f  = feat  + (size_t)bt*4096;
  const float* wr = cls_w + (size_t)k*4096;
  float s = 0.f;
  #pragma unroll
  for (int j0 = 0; j0 < 4096; j0 += 256){
    int j = j0 + lane*4;
    float4 fv = *(const float4*)(f + j);
    float4 wv = *(const float4*)(wr + j);
    s += fv.x*wv.x + fv.y*wv.y + fv.z*wv.z + fv.w*wv.w;
  }
  #pragma unroll
  for (int off=32; off>0; off>>=1) s += __shfl_down(s, off, 64);
  if (lane==0) out[bt*100 + k] = s + cls_b[k];
}

extern "C" void kernel_launch(void* const* d_in, const int* in_sizes, int n_in,
                              void* d_out, int out_size, void* d_ws, size_t ws_size,
                              hipStream_t stream){
  const float* inputs    = (const float*)d_in[0];
  const float* in_proj_w = (const float*)d_in[1];
  const float* conv_w    = (const float*)d_in[2];
  const float* conv_b    = (const float*)d_in[3];
  const float* dt_bias   = (const float*)d_in[4];
  const float* A_log     = (const float*)d_in[5];
  const float* cls_w     = (const float*)d_in[6];
  const float* cls_b     = (const float*)d_in[7];
  float* out = (float*)d_out;

  float* xg   = (float*)d_ws;                       // MTOT*192
  float* proj = xg   + (size_t)MTOT*DMODEL;         // MTOT*920
  float* wbuf = proj + (size_t)MTOT*NCH;            // MTOT*24
  float* yB   = wbuf + (size_t)MTOT*NH;             // MTOT*160
  float* feat = yB   + (size_t)MTOT*160;            // 128*4096
  float* partial = xg;                              // alias: xg dead after GEMM; 2M floats fit in 6.29M
  size_t need = ((size_t)MTOT*DMODEL + (size_t)MTOT*NCH + (size_t)MTOT*NH
               + (size_t)MTOT*160 + (size_t)128*4096) * sizeof(float);
  if (ws_size < need) return;  // loud failure rather than OOB scribble

  k_build_xg  <<<(MTOT*DMODEL + 255)/256, 256, 0, stream>>>(inputs, xg);
  k_gemm_proj <<<dim3(MTOT/64, (NCH+63)/64), 256, 0, stream>>>(xg, in_proj_w, proj);
  k_scan_w    <<<dim3(NH, BATCH), 256, 0, stream>>>(proj, dt_bias, A_log, wbuf);
  k_conv_fold <<<dim3(GLEN, BATCH), 256, 0, stream>>>(proj, conv_w, conv_b, wbuf, yB);
  k_partial   <<<dim3(BATCH*TWIN, 4), 256, 0, stream>>>(yB, partial);
  k_suffix    <<<dim3(16, BATCH), 256, 0, stream>>>(partial, feat);
  k_correct   <<<dim3(TWIN-1, BATCH), 256, 0, stream>>>(proj, conv_w, conv_b, wbuf, feat);
  k_classifier<<<dim3(BATCH*TWIN, 25), 256, 0, stream>>>(feat, cls_w, cls_b, out);
}

// Round 3
// 325.224 us; speedup vs baseline: 3.6836x; 1.4161x over previous
//
#include <hip/hip_runtime.h>
#include <math.h>

#define BATCH 16
#define TWIN 8
#define SEQIN 129
#define DMODEL 192
#define GLEN 2048           // TWIN*256
#define NH 24
#define HD 32
#define DS 128
#define NCC 896             // conv channels (x | B); dt handled separately
#define MTOT (BATCH*GLEN)   // 32768
#define PADK 40             // LDS row pitch in bf16: 80 B -> 16B-aligned, 2-way banks only

typedef __attribute__((ext_vector_type(8))) short bf16x8;
typedef __attribute__((ext_vector_type(4))) float f32x4;

__device__ __forceinline__ float softplus_f(float x){
  return x > 20.f ? x : log1pf(expf(x));
}
__device__ __forceinline__ float silu_f(float x){
  return x / (1.f + expf(-x));
}
__device__ __forceinline__ unsigned short tobf16(float f){
  union { float f; unsigned u; } v; v.f = f;
  unsigned r = v.u + 0x7FFF + ((v.u >> 16) & 1);
  return (unsigned short)(r >> 16);
}

// Build PE-added, sliced, padded input: xg (fp32) + xh (bf16), g = t*256 + s
__global__ __launch_bounds__(256) void k_build_xg(const float* __restrict__ in,
    float* __restrict__ xg, unsigned short* __restrict__ xh){
  int idx = blockIdx.x*256 + threadIdx.x;
  if (idx >= MTOT*DMODEL) return;
  int d = idx % DMODEL;
  int rest = idx / DMODEL;
  int g = rest % GLEN;
  int b = rest / GLEN;
  int t = g >> 8, s = g & 255;
  float v = 0.f;
  if (s < 128) v = in[((size_t)(b*TWIN + t)*SEQIN + (s+1))*DMODEL + d];
  float div = expf(-(float)(d & ~1) * (logf(10000.f)/(float)DMODEL));
  float ang = (float)t * div;
  v += (d & 1) ? cosf(ang) : sinf(ang);
  xg[idx] = v;
  xh[idx] = tobf16(v);
}

// bf16 copy of conv-channel weight rows: wh[c][k] = in_proj_w[768+c][k], c<896
__global__ __launch_bounds__(256) void k_conv_w_bf16(const float* __restrict__ inw,
    unsigned short* __restrict__ wh){
  int idx = blockIdx.x*256 + threadIdx.x;
  if (idx >= NCC*DMODEL) return;
  int c = idx / DMODEL, k = idx % DMODEL;
  wh[idx] = tobf16(inw[(size_t)(768 + c)*DMODEL + k]);
}

// MFMA GEMM: proj[m][c] = sum_k xh[m][k]*wh[c][k]; 128x128 tile, 4 waves
__global__ __launch_bounds__(256) void k_gemm_mfma(const unsigned short* __restrict__ xh,
    const unsigned short* __restrict__ wh, float* __restrict__ proj){
  __shared__ unsigned short As[128*PADK];
  __shared__ unsigned short Bs[128*PADK];
  int tid = threadIdx.x;
  int m0 = blockIdx.x*128, n0 = blockIdx.y*128;
  int wid = tid >> 6, lane = tid & 63;
  int wm = (wid >> 1)*64, wn = (wid & 1)*64;
  int quad = lane >> 4, lm = lane & 15;
  int sr = tid >> 2, sq = tid & 3;
  f32x4 acc[4][4];
  #pragma unroll
  for (int i=0;i<4;i++)
    #pragma unroll
    for (int j=0;j<4;j++) acc[i][j] = (f32x4){0.f,0.f,0.f,0.f};
  for (int k0 = 0; k0 < DMODEL; k0 += 32){
    #pragma unroll
    for (int half=0; half<2; half++){
      int r = sr + half*64;
      *(bf16x8*)&As[r*PADK + sq*8] =
        *(const bf16x8*)&xh[(size_t)(m0+r)*DMODEL + k0 + sq*8];
      *(bf16x8*)&Bs[r*PADK + sq*8] =
        *(const bf16x8*)&wh[(size_t)(n0+r)*DMODEL + k0 + sq*8];
    }
    __syncthreads();
    bf16x8 aF[4], bF[4];
    #pragma unroll
    for (int i=0;i<4;i++){
      aF[i] = *(const bf16x8*)&As[(wm + i*16 + lm)*PADK + quad*8];
      bF[i] = *(const bf16x8*)&Bs[(wn + i*16 + lm)*PADK + quad*8];
    }
    #pragma unroll
    for (int i=0;i<4;i++)
      #pragma unroll
      for (int j=0;j<4;j++)
        acc[i][j] = __builtin_amdgcn_mfma_f32_16x16x32_bf16(aF[i], bF[j], acc[i][j], 0,0,0);
    __syncthreads();
  }
  #pragma unroll
  for (int i=0;i<4;i++){
    #pragma unroll
    for (int r=0;r<4;r++){
      int m = m0 + wm + i*16 + quad*4 + r;
      float* dst = proj + (size_t)m*NCC + n0 + wn + lm;
      #pragma unroll
      for (int j=0;j<4;j++)
        dst[j*16] = acc[i][j][r];
    }
  }
}

// fp32 GEMM for the 24 dt channels: dtraw[m][h] = sum_k xg[m][k]*W[1792+h][k]
__global__ __launch_bounds__(256) void k_gemm_dt(const float* __restrict__ xg,
    const float* __restrict__ inw, float* __restrict__ dtraw){
  __shared__ float As[16][64];
  __shared__ float Bs[16][64];
  int tid = threadIdx.x;
  int m0 = blockIdx.x*64;
  int ty = tid >> 4, tx = tid & 15;
  int lr = tid >> 2, lq = tid & 3;
  float acc[4][4] = {};
  for (int k0 = 0; k0 < DMODEL; k0 += 16){
    float4 av = *(const float4*)(xg + (size_t)(m0+lr)*DMODEL + k0 + lq*4);
    As[lq*4+0][lr] = av.x; As[lq*4+1][lr] = av.y;
    As[lq*4+2][lr] = av.z; As[lq*4+3][lr] = av.w;
    float4 bv = make_float4(0.f,0.f,0.f,0.f);
    if (lr < NH) bv = *(const float4*)(inw + (size_t)(1792+lr)*DMODEL + k0 + lq*4);
    Bs[lq*4+0][lr] = bv.x; Bs[lq*4+1][lr] = bv.y;
    Bs[lq*4+2][lr] = bv.z; Bs[lq*4+3][lr] = bv.w;
    __syncthreads();
    #pragma unroll
    for (int kk = 0; kk < 16; kk++){
      float4 a = *(const float4*)&As[kk][ty*4];
      float4 bq = *(const float4*)&Bs[kk][tx*4];
      float avr[4] = {a.x, a.y, a.z, a.w};
      float bvr[4] = {bq.x, bq.y, bq.z, bq.w};
      #pragma unroll
      for (int i=0;i<4;i++)
        #pragma unroll
        for (int j=0;j<4;j++)
          acc[i][j] += avr[i]*bvr[j];
    }
    __syncthreads();
  }
  #pragma unroll
  for (int i=0;i<4;i++){
    int m = m0 + ty*4 + i;
    #pragma unroll
    for (int j=0;j<4;j++){
      int n = tx*4 + j;
      if (n < NH) dtraw[(size_t)m*NH + n] = acc[i][j];
    }
  }
}

// Per (b,h): w[g] = exp(csum_total - csum[g]) * dt[g]   (window-independent)
__global__ __launch_bounds__(256) void k_scan_w(const float* __restrict__ dtraw,
    const float* __restrict__ dt_bias, const float* __restrict__ A_log,
    float* __restrict__ wbuf){
  int h = blockIdx.x, b = blockIdx.y;
  int tid = threadIdx.x;
  float dtb = dt_bias[h];
  float negA = -expf(A_log[h]);
  float dtv[8], pre[8];
  float run = 0.f;
  size_t base = (size_t)b*GLEN;
  #pragma unroll
  for (int i=0;i<8;i++){
    int g = tid*8 + i;
    float v = dtraw[(base + g)*NH + h];
    float dt = softplus_f(v + dtb);
    run += dt * negA;
    dtv[i] = dt; pre[i] = run;
  }
  __shared__ float s[256];
  float tot_thread = run;
  s[tid] = run;
  __syncthreads();
  for (int off=1; off<256; off<<=1){
    float v = (tid>=off) ? s[tid-off] : 0.f;
    __syncthreads();
    s[tid] += v;
    __syncthreads();
  }
  float total = s[255];
  float excl = s[tid] - tot_thread;
  #pragma unroll
  for (int i=0;i<8;i++){
    int g = tid*8+i;
    float w = expf(total - (excl + pre[i])) * dtv[i];
    wbuf[(base + g)*NH + h] = w;
  }
}

// Global conv+silu, fold heads: yB row = [y(32)|Bm(128)]
__global__ __launch_bounds__(256) void k_conv_fold(const float* __restrict__ proj,
    const float* __restrict__ conv_w, const float* __restrict__ conv_b,
    const float* __restrict__ wbuf, float* __restrict__ yB){
  int g = blockIdx.x, b = blockIdx.y;
  int tid = threadIdx.x;
  __shared__ float xs[NCC];
  __shared__ float wv[NH];
  size_t rbase = (size_t)b*GLEN;
  if (tid < NH) wv[tid] = wbuf[(rbase + g)*NH + tid];
  for (int c = tid; c < NCC; c += 256){
    float a = conv_b[c];
    #pragma unroll
    for (int k=0;k<4;k++){
      int gp = g - 3 + k;
      if (gp >= 0) a += proj[(rbase+gp)*NCC + c] * conv_w[c*4+k];
    }
    xs[c] = silu_f(a);
  }
  __syncthreads();
  if (tid < 32){
    float y = 0.f;
    #pragma unroll
    for (int h=0;h<NH;h++) y += wv[h]*xs[h*32+tid];
    yB[(rbase+g)*160 + tid] = y;
  } else if (tid < 160){
    yB[(rbase+g)*160 + tid] = xs[768 + tid - 32];
  }
}

// Chunk partials: partial[b][t][sub][32][128] over 64 positions each
__global__ __launch_bounds__(256) void k_partial(const float* __restrict__ yB,
    float* __restrict__ partial){
  int t = blockIdx.x & 7, b = blockIdx.x >> 3, sub = blockIdx.y;
  int tid = threadIdx.x;
  __shared__ float buf[8*160];
  int p0 = (tid >> 5) * 4;
  int n0 = (tid & 31) * 4;
  float acc[4][4] = {};
  size_t rbase = (size_t)b*GLEN;
  int gstart = t*256 + sub*64;
  for (int gb = gstart; gb < gstart+64; gb += 8){
    for (int idx = tid; idx < 8*160; idx += 256)
      buf[idx] = yB[(rbase+gb)*160 + idx];
    __syncthreads();
    #pragma unroll
    for (int gi=0; gi<8; gi++){
      float4 yv = *(const float4*)&buf[gi*160 + p0];
      float4 bv = *(const float4*)&buf[gi*160 + 32 + n0];
      float ya[4] = {yv.x,yv.y,yv.z,yv.w};
      float ba[4] = {bv.x,bv.y,bv.z,bv.w};
      #pragma unroll
      for (int i=0;i<4;i++)
        #pragma unroll
        for (int j=0;j<4;j++)
          acc[i][j] += ya[i]*ba[j];
    }
    __syncthreads();
  }
  size_t pb = (((size_t)(b*TWIN + t))*4 + sub)*4096;
  #pragma unroll
  for (int i=0;i<4;i++)
    #pragma unroll
    for (int j=0;j<4;j++)
      partial[pb + (p0+i)*128 + n0+j] = acc[i][j];
}

// Suffix-sum partials over t
__global__ __launch_bounds__(256) void k_suffix(const float* __restrict__ partial,
    float* __restrict__ feat){
  int b = blockIdx.y;
  int e = blockIdx.x*256 + threadIdx.x;   // 0..4095
  float s = 0.f;
  for (int t = TWIN-1; t >= 0; t--){
    size_t pb = ((size_t)(b*TWIN + t))*4*4096;
    #pragma unroll
    for (int sub=0; sub<4; sub++) s += partial[pb + sub*4096 + e];
    feat[((size_t)(b*TWIN + t))*4096 + e] = s;
  }
}

// Boundary corrections for t>0: first 3 positions use zero-history conv
__global__ __launch_bounds__(256) void k_correct(const float* __restrict__ proj,
    const float* __restrict__ conv_w, const float* __restrict__ conv_b,
    const float* __restrict__ wbuf, float* __restrict__ feat){
  int t = blockIdx.x + 1, b = blockIdx.y;
  int tid = threadIdx.x;
  __shared__ float xsw[NCC], xsg[NCC];
  __shared__ float wv[NH];
  __shared__ float bufw[3*160], bufg[3*160];
  size_t rbase = (size_t)b*GLEN;
  int g0 = t*256;
  for (int gi=0; gi<3; gi++){
    int g = g0 + gi;
    if (tid < NH) wv[tid] = wbuf[(rbase+g)*NH + tid];
    for (int c = tid; c < NCC; c += 256){
      float aw = conv_b[c], ag = conv_b[c];
      #pragma unroll
      for (int k=0;k<4;k++){
        int gp = g - 3 + k;
        float term = proj[(rbase+gp)*NCC + c] * conv_w[c*4+k];
        ag += term;
        if (gp >= g0) aw += term;
      }
      xsw[c] = silu_f(aw);
      xsg[c] = silu_f(ag);
    }
    __syncthreads();
    if (tid < 32){
      float yw = 0.f, yg = 0.f;
      #pragma unroll
      for (int h=0;h<NH;h++){ yw += wv[h]*xsw[h*32+tid]; yg += wv[h]*xsg[h*32+tid]; }
      bufw[gi*160 + tid] = yw;
      bufg[gi*160 + tid] = yg;
    } else if (tid < 160){
      bufw[gi*160 + tid] = xsw[768 + tid - 32];
      bufg[gi*160 + tid] = xsg[768 + tid - 32];
    }
    __syncthreads();
  }
  int p0 = (tid >> 5) * 4;
  int n0 = (tid & 31) * 4;
  float acc[4][4] = {};
  #pragma unroll
  for (int gi=0; gi<3; gi++){
    float4 ywv = *(const float4*)&bufw[gi*160 + p0];
    float4 bwv = *(const float4*)&bufw[gi*160 + 32 + n0];
    float4 ygv = *(const float4*)&bufg[gi*160 + p0];
    float4 bgv = *(const float4*)&bufg[gi*160 + 32 + n0];
    float yw[4]={ywv.x,ywv.y,ywv.z,ywv.w}, bw[4]={bwv.x,bwv.y,bwv.z,bwv.w};
    float yg[4]={ygv.x,ygv.y,ygv.z,ygv.w}, bg[4]={bgv.x,bgv.y,bgv.z,bgv.w};
    #pragma unroll
    for (int i=0;i<4;i++)
      #pragma unroll
      for (int j=0;j<4;j++)
        acc[i][j] += yw[i]*bw[j] - yg[i]*bg[j];
  }
  size_t fb = (size_t)(b*TWIN + t)*4096;
  #pragma unroll
  for (int i=0;i<4;i++)
    #pragma unroll
    for (int j=0;j<4;j++)
      feat[fb + (p0+i)*128 + n0+j] += acc[i][j];
}

// out[bt][k] = feat[bt] . cls_w[k] + cls_b[k]; one wave per (bt,k)
__global__ __launch_bounds__(256) void k_classifier(const float* __restrict__ feat,
    const float* __restrict__ cls_w, const float* __restrict__ cls_b,
    float* __restrict__ out){
  int bt = blockIdx.x;
  int wave = threadIdx.x >> 6, lane = threadIdx.x & 63;
  int k = blockIdx.y*4 + wave;
  if (k >= 100) return;
  const float* f  = feat  + (size_t)bt*4096;
  const float* wr = cls_w + (size_t)k*4096;
  float s = 0.f;
  #pragma unroll
  for (int j0 = 0; j0 < 4096; j0 += 256){
    int j = j0 + lane*4;
    float4 fv = *(const float4*)(f + j);
    float4 wv = *(const float4*)(wr + j);
    s += fv.x*wv.x + fv.y*wv.y + fv.z*wv.z + fv.w*wv.w;
  }
  #pragma unroll
  for (int off=32; off>0; off>>=1) s += __shfl_down(s, off, 64);
  if (lane==0) out[bt*100 + k] = s + cls_b[k];
}

extern "C" void kernel_launch(void* const* d_in, const int* in_sizes, int n_in,
                              void* d_out, int out_size, void* d_ws, size_t ws_size,
                              hipStream_t stream){
  const float* inputs    = (const float*)d_in[0];
  const float* in_proj_w = (const float*)d_in[1];
  const float* conv_w    = (const float*)d_in[2];
  const float* conv_b    = (const float*)d_in[3];
  const float* dt_bias   = (const float*)d_in[4];
  const float* A_log     = (const float*)d_in[5];
  const float* cls_w     = (const float*)d_in[6];
  const float* cls_b     = (const float*)d_in[7];
  float* out = (float*)d_out;

  float* xg    = (float*)d_ws;                      // MTOT*192
  float* proj  = xg    + (size_t)MTOT*DMODEL;       // MTOT*896
  float* dtraw = proj  + (size_t)MTOT*NCC;          // MTOT*24
  float* wbuf  = dtraw + (size_t)MTOT*NH;           // MTOT*24
  float* yB    = wbuf  + (size_t)MTOT*NH;           // MTOT*160
  float* feat  = yB    + (size_t)MTOT*160;          // 128*4096
  // aliases over dead regions:
  unsigned short* xh = (unsigned short*)yB;         // 12.6 MB, dead before yB written
  unsigned short* wh = xh + (size_t)MTOT*DMODEL;    // +0.34 MB, still < yB's 21 MB
  float* partial = xg;                              // xg dead after k_gemm_dt
  size_t need = ((size_t)MTOT*(DMODEL + NCC + NH + NH + 160) + (size_t)128*4096)
              * sizeof(float);
  if (ws_size < need) return;

  k_build_xg   <<<(MTOT*DMODEL + 255)/256, 256, 0, stream>>>(inputs, xg, xh);
  k_conv_w_bf16<<<(NCC*DMODEL + 255)/256, 256, 0, stream>>>(in_proj_w, wh);
  k_gemm_mfma  <<<dim3(MTOT/128, NCC/128), 256, 0, stream>>>(xh, wh, proj);
  k_gemm_dt    <<<dim3(MTOT/64, 1), 256, 0, stream>>>(xg, in_proj_w, dtraw);
  k_scan_w     <<<dim3(NH, BATCH), 256, 0, stream>>>(dtraw, dt_bias, A_log, wbuf);
  k_conv_fold  <<<dim3(GLEN, BATCH), 256, 0, stream>>>(proj, conv_w, conv_b, wbuf, yB);
  k_partial    <<<dim3(BATCH*TWIN, 4), 256, 0, stream>>>(yB, partial);
  k_suffix     <<<dim3(16, BATCH), 256, 0, stream>>>(partial, feat);
  k_correct    <<<dim3(TWIN-1, BATCH), 256, 0, stream>>>(proj, conv_w, conv_b, wbuf, feat);
  k_classifier <<<dim3(BATCH*TWIN, 25), 256, 0, stream>>>(feat, cls_w, cls_b, out);
}

// Round 4
// 254.771 us; speedup vs baseline: 4.7023x; 1.2765x over previous
//
#include <hip/hip_runtime.h>
#include <math.h>

#define BATCH 16
#define TWIN 8
#define SEQIN 129
#define DMODEL 192
#define GLEN 2048           // TWIN*256
#define NH 24
#define HD 32
#define DS 128
#define NCC 896             // conv channels (x | B); dt handled separately
#define MTOT (BATCH*GLEN)   // 32768
#define PADK 40             // GEMM LDS row pitch in bf16

typedef __attribute__((ext_vector_type(8))) short bf16x8;
typedef __attribute__((ext_vector_type(4))) float f32x4;

__device__ __forceinline__ float softplus_f(float x){
  return x > 20.f ? x : log1pf(expf(x));
}
__device__ __forceinline__ float silu_f(float x){
  return x / (1.f + expf(-x));
}
__device__ __forceinline__ unsigned short tobf16(float f){
  union { float f; unsigned u; } v; v.f = f;
  unsigned r = v.u + 0x7FFF + ((v.u >> 16) & 1);
  return (unsigned short)(r >> 16);
}
__device__ __forceinline__ float frombf16(unsigned short u){
  union { unsigned u; float f; } v; v.u = ((unsigned)u) << 16; return v.f;
}

// Build PE-added, sliced, padded input: xg (fp32) + xh (bf16)
__global__ __launch_bounds__(256) void k_build_xg(const float* __restrict__ in,
    float* __restrict__ xg, unsigned short* __restrict__ xh){
  int idx = blockIdx.x*256 + threadIdx.x;
  if (idx >= MTOT*DMODEL) return;
  int d = idx % DMODEL;
  int rest = idx / DMODEL;
  int g = rest % GLEN;
  int b = rest / GLEN;
  int t = g >> 8, s = g & 255;
  float v = 0.f;
  if (s < 128) v = in[((size_t)(b*TWIN + t)*SEQIN + (s+1))*DMODEL + d];
  float div = expf(-(float)(d & ~1) * (logf(10000.f)/(float)DMODEL));
  float ang = (float)t * div;
  v += (d & 1) ? cosf(ang) : sinf(ang);
  xg[idx] = v;
  xh[idx] = tobf16(v);
}

// bf16 copy of conv-channel weight rows
__global__ __launch_bounds__(256) void k_conv_w_bf16(const float* __restrict__ inw,
    unsigned short* __restrict__ wh){
  int idx = blockIdx.x*256 + threadIdx.x;
  if (idx >= NCC*DMODEL) return;
  int c = idx / DMODEL, k = idx % DMODEL;
  wh[idx] = tobf16(inw[(size_t)(768 + c)*DMODEL + k]);
}

// MFMA GEMM: projh[m][c] = bf16( sum_k xh[m][k]*wh[c][k] )
__global__ __launch_bounds__(256) void k_gemm_mfma(const unsigned short* __restrict__ xh,
    const unsigned short* __restrict__ wh, unsigned short* __restrict__ projh){
  __shared__ unsigned short As[128*PADK];
  __shared__ unsigned short Bs[128*PADK];
  int tid = threadIdx.x;
  int m0 = blockIdx.x*128, n0 = blockIdx.y*128;
  int wid = tid >> 6, lane = tid & 63;
  int wm = (wid >> 1)*64, wn = (wid & 1)*64;
  int quad = lane >> 4, lm = lane & 15;
  int sr = tid >> 2, sq = tid & 3;
  f32x4 acc[4][4];
  #pragma unroll
  for (int i=0;i<4;i++)
    #pragma unroll
    for (int j=0;j<4;j++) acc[i][j] = (f32x4){0.f,0.f,0.f,0.f};
  for (int k0 = 0; k0 < DMODEL; k0 += 32){
    #pragma unroll
    for (int half=0; half<2; half++){
      int r = sr + half*64;
      *(bf16x8*)&As[r*PADK + sq*8] =
        *(const bf16x8*)&xh[(size_t)(m0+r)*DMODEL + k0 + sq*8];
      *(bf16x8*)&Bs[r*PADK + sq*8] =
        *(const bf16x8*)&wh[(size_t)(n0+r)*DMODEL + k0 + sq*8];
    }
    __syncthreads();
    bf16x8 aF[4], bF[4];
    #pragma unroll
    for (int i=0;i<4;i++){
      aF[i] = *(const bf16x8*)&As[(wm + i*16 + lm)*PADK + quad*8];
      bF[i] = *(const bf16x8*)&Bs[(wn + i*16 + lm)*PADK + quad*8];
    }
    #pragma unroll
    for (int i=0;i<4;i++)
      #pragma unroll
      for (int j=0;j<4;j++)
        acc[i][j] = __builtin_amdgcn_mfma_f32_16x16x32_bf16(aF[i], bF[j], acc[i][j], 0,0,0);
    __syncthreads();
  }
  #pragma unroll
  for (int i=0;i<4;i++){
    #pragma unroll
    for (int r=0;r<4;r++){
      int m = m0 + wm + i*16 + quad*4 + r;
      unsigned short* dst = projh + (size_t)m*NCC + n0 + wn + lm;
      #pragma unroll
      for (int j=0;j<4;j++)
        dst[j*16] = tobf16(acc[i][j][r]);
    }
  }
}

// fp32 GEMM for the 24 dt channels (kept fp32: exponent amplification)
__global__ __launch_bounds__(256) void k_gemm_dt(const float* __restrict__ xg,
    const float* __restrict__ inw, float* __restrict__ dtraw){
  __shared__ float As[16][64];
  __shared__ float Bs[16][64];
  int tid = threadIdx.x;
  int m0 = blockIdx.x*64;
  int ty = tid >> 4, tx = tid & 15;
  int lr = tid >> 2, lq = tid & 3;
  float acc[4][4] = {};
  for (int k0 = 0; k0 < DMODEL; k0 += 16){
    float4 av = *(const float4*)(xg + (size_t)(m0+lr)*DMODEL + k0 + lq*4);
    As[lq*4+0][lr] = av.x; As[lq*4+1][lr] = av.y;
    As[lq*4+2][lr] = av.z; As[lq*4+3][lr] = av.w;
    float4 bv = make_float4(0.f,0.f,0.f,0.f);
    if (lr < NH) bv = *(const float4*)(inw + (size_t)(1792+lr)*DMODEL + k0 + lq*4);
    Bs[lq*4+0][lr] = bv.x; Bs[lq*4+1][lr] = bv.y;
    Bs[lq*4+2][lr] = bv.z; Bs[lq*4+3][lr] = bv.w;
    __syncthreads();
    #pragma unroll
    for (int kk = 0; kk < 16; kk++){
      float4 a = *(const float4*)&As[kk][ty*4];
      float4 bq = *(const float4*)&Bs[kk][tx*4];
      float avr[4] = {a.x, a.y, a.z, a.w};
      float bvr[4] = {bq.x, bq.y, bq.z, bq.w};
      #pragma unroll
      for (int i=0;i<4;i++)
        #pragma unroll
        for (int j=0;j<4;j++)
          acc[i][j] += avr[i]*bvr[j];
    }
    __syncthreads();
  }
  #pragma unroll
  for (int i=0;i<4;i++){
    int m = m0 + ty*4 + i;
    #pragma unroll
    for (int j=0;j<4;j++){
      int n = tx*4 + j;
      if (n < NH) dtraw[(size_t)m*NH + n] = acc[i][j];
    }
  }
}

// Per (b,h): w[g] = exp(csum_total - csum[g]) * dt[g]
__global__ __launch_bounds__(256) void k_scan_w(const float* __restrict__ dtraw,
    const float* __restrict__ dt_bias, const float* __restrict__ A_log,
    float* __restrict__ wbuf){
  int h = blockIdx.x, b = blockIdx.y;
  int tid = threadIdx.x;
  float dtb = dt_bias[h];
  float negA = -expf(A_log[h]);
  float dtv[8], pre[8];
  float run = 0.f;
  size_t base = (size_t)b*GLEN;
  #pragma unroll
  for (int i=0;i<8;i++){
    int g = tid*8 + i;
    float v = dtraw[(base + g)*NH + h];
    float dt = softplus_f(v + dtb);
    run += dt * negA;
    dtv[i] = dt; pre[i] = run;
  }
  __shared__ float s[256];
  float tot_thread = run;
  s[tid] = run;
  __syncthreads();
  for (int off=1; off<256; off<<=1){
    float v = (tid>=off) ? s[tid-off] : 0.f;
    __syncthreads();
    s[tid] += v;
    __syncthreads();
  }
  float total = s[255];
  float excl = s[tid] - tot_thread;
  #pragma unroll
  for (int i=0;i<8;i++){
    int g = tid*8+i;
    float w = expf(total - (excl + pre[i])) * dtv[i];
    wbuf[(base + g)*NH + h] = w;
  }
}

// Fused conv+silu+fold+partial outer product. Block = (b, 64-position range).
// proj rows stream through an LDS ring buffer exactly once.
__global__ __launch_bounds__(256) void k_conv_fuse(const unsigned short* __restrict__ projh,
    const float* __restrict__ conv_w, const float* __restrict__ conv_b,
    const float* __restrict__ wbuf, float* __restrict__ partial){
  int qblk = blockIdx.x;      // 0..31 (64-pos quarter-windows)
  int b = blockIdx.y;
  int tid = threadIdx.x;
  __shared__ unsigned short ring[12*NCC];   // bf16 proj rows, slot = g % 12
  __shared__ float xs[8*900];               // silu(conv) for the 8-pos chunk, pitch 900
  __shared__ float ybuf[8*160];             // [y(32)|Bm(128)] per chunk pos
  __shared__ float wv[8*NH];
  size_t rbase = (size_t)b*GLEN;
  int gblk = qblk*64;
  float acc[4][4] = {};
  int p0 = (tid >> 5)*4, n0 = (tid & 31)*4;
  int cgi = tid >> 5;          // position-within-chunk group (8 groups of 32 lanes)
  int clane = tid & 31;
  for (int ch = 0; ch < 8; ch++){
    int g0 = gblk + ch*8;
    int gstart = (ch == 0) ? g0 - 3 : g0;
    int nrows  = (ch == 0) ? 11 : 8;
    if (gstart < 0){ nrows += gstart; gstart = 0; }
    int nvec = nrows*224;      // ushort4 per row = 896/4
    for (int idx = tid; idx < nvec; idx += 256){
      int ri = idx / 224, c4 = idx - ri*224;
      int g = gstart + ri;
      int slot = g % 12;
      *(ushort4*)&ring[slot*NCC + c4*4] =
        *(const ushort4*)&projh[(rbase + g)*NCC + c4*4];
    }
    if (tid < 8*NH){
      int gi = tid / NH, h = tid - (tid/NH)*NH;
      wv[gi*NH + h] = wbuf[(rbase + g0 + gi)*NH + h];
    }
    __syncthreads();
    // conv + silu into xs
    {
      int g = g0 + cgi;
      #pragma unroll
      for (int j = 0; j < 7; j++){
        int c = clane*4 + j*128;
        float4 cbv = *(const float4*)&conv_b[c];
        float a0 = cbv.x, a1 = cbv.y, a2 = cbv.z, a3 = cbv.w;
        float4 w0 = *(const float4*)&conv_w[(c+0)*4];
        float4 w1 = *(const float4*)&conv_w[(c+1)*4];
        float4 w2 = *(const float4*)&conv_w[(c+2)*4];
        float4 w3 = *(const float4*)&conv_w[(c+3)*4];
        float cw0[4] = {w0.x,w0.y,w0.z,w0.w};
        float cw1[4] = {w1.x,w1.y,w1.z,w1.w};
        float cw2[4] = {w2.x,w2.y,w2.z,w2.w};
        float cw3[4] = {w3.x,w3.y,w3.z,w3.w};
        #pragma unroll
        for (int k = 0; k < 4; k++){
          int gp = g - 3 + k;
          if (gp >= 0){
            int slot = gp % 12;
            ushort4 pv = *(const ushort4*)&ring[slot*NCC + c];
            a0 += frombf16(pv.x)*cw0[k];
            a1 += frombf16(pv.y)*cw1[k];
            a2 += frombf16(pv.z)*cw2[k];
            a3 += frombf16(pv.w)*cw3[k];
          }
        }
        float4 o = make_float4(silu_f(a0), silu_f(a1), silu_f(a2), silu_f(a3));
        *(float4*)&xs[cgi*900 + c] = o;
      }
    }
    __syncthreads();
    // fold heads + copy Bm
    {
      float y = 0.f;
      #pragma unroll
      for (int h = 0; h < NH; h++)
        y += wv[cgi*NH + h] * xs[cgi*900 + h*32 + clane];
      ybuf[cgi*160 + clane] = y;
      #pragma unroll
      for (int j = 0; j < 4; j++)
        ybuf[cgi*160 + 32 + clane + j*32] = xs[cgi*900 + 768 + clane + j*32];
    }
    __syncthreads();
    // accumulate outer products (no barrier after: next-load regions disjoint)
    #pragma unroll
    for (int gi = 0; gi < 8; gi++){
      float4 yv = *(const float4*)&ybuf[gi*160 + p0];
      float4 bv = *(const float4*)&ybuf[gi*160 + 32 + n0];
      float ya[4] = {yv.x,yv.y,yv.z,yv.w};
      float ba[4] = {bv.x,bv.y,bv.z,bv.w};
      #pragma unroll
      for (int i=0;i<4;i++)
        #pragma unroll
        for (int j=0;j<4;j++)
          acc[i][j] += ya[i]*ba[j];
    }
  }
  size_t pb = ((size_t)(b*32 + qblk))*4096;
  #pragma unroll
  for (int i=0;i<4;i++)
    #pragma unroll
    for (int j=0;j<4;j++)
      partial[pb + (p0+i)*128 + n0+j] = acc[i][j];
}

// Suffix-sum quarter partials: feat[b][t] = sum_{q>=4t} partial[b][q]
__global__ __launch_bounds__(256) void k_suffix(const float* __restrict__ partial,
    float* __restrict__ feat){
  int b = blockIdx.y;
  int e = blockIdx.x*256 + threadIdx.x;   // 0..4095
  float s = 0.f;
  for (int q = 31; q >= 0; q--){
    s += partial[((size_t)(b*32 + q))*4096 + e];
    if ((q & 3) == 0)
      feat[((size_t)(b*TWIN + (q >> 2)))*4096 + e] = s;
  }
}

// Boundary corrections for t>0
__global__ __launch_bounds__(256) void k_correct(const unsigned short* __restrict__ projh,
    const float* __restrict__ conv_w, const float* __restrict__ conv_b,
    const float* __restrict__ wbuf, float* __restrict__ feat){
  int t = blockIdx.x + 1, b = blockIdx.y;
  int tid = threadIdx.x;
  __shared__ float xsw[NCC], xsg[NCC];
  __shared__ float wv[NH];
  __shared__ float bufw[3*160], bufg[3*160];
  size_t rbase = (size_t)b*GLEN;
  int g0 = t*256;
  for (int gi=0; gi<3; gi++){
    int g = g0 + gi;
    if (tid < NH) wv[tid] = wbuf[(rbase+g)*NH + tid];
    for (int c = tid; c < NCC; c += 256){
      float aw = conv_b[c], ag = conv_b[c];
      #pragma unroll
      for (int k=0;k<4;k++){
        int gp = g - 3 + k;
        float term = frombf16(projh[(rbase+gp)*NCC + c]) * conv_w[c*4+k];
        ag += term;
        if (gp >= g0) aw += term;
      }
      xsw[c] = silu_f(aw);
      xsg[c] = silu_f(ag);
    }
    __syncthreads();
    if (tid < 32){
      float yw = 0.f, yg = 0.f;
      #pragma unroll
      for (int h=0;h<NH;h++){ yw += wv[h]*xsw[h*32+tid]; yg += wv[h]*xsg[h*32+tid]; }
      bufw[gi*160 + tid] = yw;
      bufg[gi*160 + tid] = yg;
    } else if (tid < 160){
      bufw[gi*160 + tid] = xsw[768 + tid - 32];
      bufg[gi*160 + tid] = xsg[768 + tid - 32];
    }
    __syncthreads();
  }
  int p0 = (tid >> 5) * 4;
  int n0 = (tid & 31) * 4;
  float acc[4][4] = {};
  #pragma unroll
  for (int gi=0; gi<3; gi++){
    float4 ywv = *(const float4*)&bufw[gi*160 + p0];
    float4 bwv = *(const float4*)&bufw[gi*160 + 32 + n0];
    float4 ygv = *(const float4*)&bufg[gi*160 + p0];
    float4 bgv = *(const float4*)&bufg[gi*160 + 32 + n0];
    float yw[4]={ywv.x,ywv.y,ywv.z,ywv.w}, bw[4]={bwv.x,bwv.y,bwv.z,bwv.w};
    float yg[4]={ygv.x,ygv.y,ygv.z,ygv.w}, bg[4]={bgv.x,bgv.y,bgv.z,bgv.w};
    #pragma unroll
    for (int i=0;i<4;i++)
      #pragma unroll
      for (int j=0;j<4;j++)
        acc[i][j] += yw[i]*bw[j] - yg[i]*bg[j];
  }
  size_t fb = (size_t)(b*TWIN + t)*4096;
  #pragma unroll
  for (int i=0;i<4;i++)
    #pragma unroll
    for (int j=0;j<4;j++)
      feat[fb + (p0+i)*128 + n0+j] += acc[i][j];
}

// out[bt][k] = feat[bt] . cls_w[k] + cls_b[k]; one wave per (bt,k)
__global__ __launch_bounds__(256) void k_classifier(const float* __restrict__ feat,
    const float* __restrict__ cls_w, const float* __restrict__ cls_b,
    float* __restrict__ out){
  int bt = blockIdx.x;
  int wave = threadIdx.x >> 6, lane = threadIdx.x & 63;
  int k = blockIdx.y*4 + wave;
  if (k >= 100) return;
  const float* f  = feat  + (size_t)bt*4096;
  const float* wr = cls_w + (size_t)k*4096;
  float s = 0.f;
  #pragma unroll
  for (int j0 = 0; j0 < 4096; j0 += 256){
    int j = j0 + lane*4;
    float4 fv = *(const float4*)(f + j);
    float4 wv = *(const float4*)(wr + j);
    s += fv.x*wv.x + fv.y*wv.y + fv.z*wv.z + fv.w*wv.w;
  }
  #pragma unroll
  for (int off=32; off>0; off>>=1) s += __shfl_down(s, off, 64);
  if (lane==0) out[bt*100 + k] = s + cls_b[k];
}

extern "C" void kernel_launch(void* const* d_in, const int* in_sizes, int n_in,
                              void* d_out, int out_size, void* d_ws, size_t ws_size,
                              hipStream_t stream){
  const float* inputs    = (const float*)d_in[0];
  const float* in_proj_w = (const float*)d_in[1];
  const float* conv_w    = (const float*)d_in[2];
  const float* conv_b    = (const float*)d_in[3];
  const float* dt_bias   = (const float*)d_in[4];
  const float* A_log     = (const float*)d_in[5];
  const float* cls_w     = (const float*)d_in[6];
  const float* cls_b     = (const float*)d_in[7];
  float* out = (float*)d_out;

  float* xg            = (float*)d_ws;                          // MTOT*192 f32
  unsigned short* projh= (unsigned short*)(xg + (size_t)MTOT*DMODEL); // MTOT*896 bf16
  float* dtraw         = (float*)(projh + (size_t)MTOT*NCC);    // MTOT*24 f32
  float* wbuf          = dtraw + (size_t)MTOT*NH;               // MTOT*24 f32
  unsigned short* xh   = (unsigned short*)(wbuf + (size_t)MTOT*NH); // MTOT*192 bf16
  unsigned short* wh   = xh + (size_t)MTOT*DMODEL;              // NCC*192 bf16
  float* partial       = (float*)(wh + (size_t)NCC*DMODEL);     // 512*4096 f32
  float* feat          = partial + (size_t)512*4096;            // 128*4096 f32
  size_t need = (size_t)(feat + (size_t)128*4096 - (float*)d_ws) * sizeof(float);
  if (ws_size < need) return;

  k_build_xg   <<<(MTOT*DMODEL + 255)/256, 256, 0, stream>>>(inputs, xg, xh);
  k_conv_w_bf16<<<(NCC*DMODEL + 255)/256, 256, 0, stream>>>(in_proj_w, wh);
  k_gemm_mfma  <<<dim3(MTOT/128, NCC/128), 256, 0, stream>>>(xh, wh, projh);
  k_gemm_dt    <<<dim3(MTOT/64, 1), 256, 0, stream>>>(xg, in_proj_w, dtraw);
  k_scan_w     <<<dim3(NH, BATCH), 256, 0, stream>>>(dtraw, dt_bias, A_log, wbuf);
  k_conv_fuse  <<<dim3(32, BATCH), 256, 0, stream>>>(projh, conv_w, conv_b, wbuf, partial);
  k_suffix     <<<dim3(16, BATCH), 256, 0, stream>>>(partial, feat);
  k_correct    <<<dim3(TWIN-1, BATCH), 256, 0, stream>>>(projh, conv_w, conv_b, wbuf, feat);
  k_classifier <<<dim3(BATCH*TWIN, 25), 256, 0, stream>>>(feat, cls_w, cls_b, out);
}